// Round 2
// baseline (62.233 us; speedup 1.0000x reference)
//
#include <hip/hip_runtime.h>

#define BATCH 32
#define LATENT 128
#define NODE_DIM 8
#define MAX_NODES 512
#define H_NODE 128
#define H_EDGE 64
#define TILE 64
#define NTILE (MAX_NODES / TILE)            // 8
#define NUPPER (NTILE * (NTILE + 1) / 2)    // 36
#define UVPAD 68                            // 16B-aligned row stride, rotates banks

// ---------------------------------------------------------------------------
// Kernel A: node generator.  h = relu(z@W1+b1); nodes = h@W2+b2.
// Grid (BATCH, 8); 128 threads. Each thread produces 4 consecutive outputs
// via float4 W2 loads (fully coalesced 2KB/wave-instr).
// ---------------------------------------------------------------------------
__global__ __launch_bounds__(128) void node_gen(
    const float* __restrict__ z,  const float* __restrict__ W1,
    const float* __restrict__ b1, const float* __restrict__ W2,
    const float* __restrict__ b2, float* __restrict__ nodes_out)
{
    const int b      = blockIdx.x;
    const int mslice = blockIdx.y;   // 0..7
    const int tid    = threadIdx.x;  // 0..127

    __shared__ float sz[LATENT];
    __shared__ float sh[H_NODE];

    sz[tid] = z[b * LATENT + tid];
    __syncthreads();

    float acc = b1[tid];
#pragma unroll 8
    for (int k = 0; k < LATENT; ++k)
        acc += sz[k] * W1[k * H_NODE + tid];
    sh[tid] = fmaxf(acc, 0.0f);
    __syncthreads();

    const int m0 = mslice * 512 + tid * 4;
    float4 a = *(const float4*)&b2[m0];
    const float* w2p = &W2[m0];

#pragma unroll 4
    for (int k = 0; k < H_NODE; ++k) {
        const float hk = sh[k];
        const float4 w = *(const float4*)&w2p[(size_t)k * (MAX_NODES * NODE_DIM)];
        a.x += hk * w.x; a.y += hk * w.y; a.z += hk * w.z; a.w += hk * w.w;
    }
    *(float4*)&nodes_out[(size_t)b * (MAX_NODES * NODE_DIM) + m0] = a;
}

// ---------------------------------------------------------------------------
// Kernel B: edge generator + adjacency.
// Upper-tri 64x64 tiles. U[i][c] = eb1[c]+nodes_i·E1[:8,c]; V[j][c]=nodes_j·E1[8:,c].
// 4x4 register blocking: thread owns i in {il,il+16,il+32,il+48}, j in j0..j0+3.
// float4 LDS reads; P aliased onto dead U; transpose mirror via LDS.
// ---------------------------------------------------------------------------
__global__ __launch_bounds__(256) void edge_gen(
    const float* __restrict__ nodes, const float* __restrict__ E1,
    const float* __restrict__ eb1,   const float* __restrict__ E2,
    const float* __restrict__ eb2,   float* __restrict__ adj)
{
    const int b = blockIdx.y;
    int rem = blockIdx.x;            // 0..35 -> (bi, bj) with bi <= bj
    int bi = 0;
    while (rem >= NTILE - bi) { rem -= NTILE - bi; ++bi; }
    const int bj = bi + rem;

    const int tid = threadIdx.x;     // 0..255
    const int il  = tid & 15;        // i base (i = il + 16m)
    const int j0  = (tid >> 4) << 2; // j block of 4

    __shared__ float U[TILE][UVPAD];
    __shared__ float V[TILE][UVPAD];
    __shared__ float sN[2][TILE][NODE_DIM];
    __shared__ float sE1[2 * NODE_DIM][H_EDGE];
    __shared__ float sE2[H_EDGE];
    __shared__ float sEb1[H_EDGE];

    // ---- stage constants + node rows ----
    for (int idx = tid; idx < 2 * NODE_DIM * H_EDGE; idx += 256)
        (&sE1[0][0])[idx] = E1[idx];
    if (tid < H_EDGE) { sE2[tid] = E2[tid]; sEb1[tid] = eb1[tid]; }

    const float* nb = nodes + (size_t)b * MAX_NODES * NODE_DIM;
    for (int idx = tid; idx < TILE * NODE_DIM; idx += 256) {
        (&sN[0][0][0])[idx] = nb[bi * TILE * NODE_DIM + idx];
        (&sN[1][0][0])[idx] = nb[bj * TILE * NODE_DIM + idx];
    }
    __syncthreads();

    // ---- U, V: per wave, i uniform (broadcast sN), c = lane (coalesced) ----
    for (int idx = tid; idx < TILE * H_EDGE; idx += 256) {
        const int i = idx >> 6, c = idx & 63;
        float au = sEb1[c], av = 0.0f;
#pragma unroll
        for (int d = 0; d < NODE_DIM; ++d) {
            au += sN[0][i][d] * sE1[d][c];
            av += sN[1][i][d] * sE1[NODE_DIM + d][c];
        }
        U[i][c] = au;
        V[i][c] = av;
    }
    __syncthreads();

    // ---- main compute: 16 pairs/thread, float4 over channels ----
    float acc[4][4];
#pragma unroll
    for (int m = 0; m < 4; ++m)
#pragma unroll
        for (int j = 0; j < 4; ++j) acc[m][j] = 0.0f;

#pragma unroll 2
    for (int cb = 0; cb < H_EDGE / 4; ++cb) {
        const float4 w = *(const float4*)&sE2[cb * 4];
        float4 u[4], v[4];
#pragma unroll
        for (int m = 0; m < 4; ++m)
            u[m] = *(const float4*)&U[il + 16 * m][cb * 4];
#pragma unroll
        for (int j = 0; j < 4; ++j)
            v[j] = *(const float4*)&V[j0 + j][cb * 4];

#pragma unroll
        for (int m = 0; m < 4; ++m) {
#pragma unroll
            for (int j = 0; j < 4; ++j) {
                acc[m][j] += w.x * fmaxf(u[m].x + v[j].x, 0.0f);
                acc[m][j] += w.y * fmaxf(u[m].y + v[j].y, 0.0f);
                acc[m][j] += w.z * fmaxf(u[m].z + v[j].z, 0.0f);
                acc[m][j] += w.w * fmaxf(u[m].w + v[j].w, 0.0f);
            }
        }
    }

    __syncthreads();                       // all U reads done; safe to overwrite
    float (*P)[UVPAD] = U;                 // alias P onto dead U
    const float bias = eb2[0];
#pragma unroll
    for (int m = 0; m < 4; ++m)
#pragma unroll
        for (int j = 0; j < 4; ++j) {
            const float x = acc[m][j] + bias;
            P[il + 16 * m][j0 + j] = 1.0f / (1.0f + __expf(-x));
        }
    __syncthreads();

    // ---- write adj (and mirror) ----
    float* adjb = adj + (size_t)b * MAX_NODES * MAX_NODES;
    if (bi != bj) {
        for (int idx = tid; idx < TILE * 16; idx += 256) {   // 4 iters
            const int r = idx >> 4, cb = idx & 15;
            const float4 pv = *(const float4*)&P[r][cb * 4];
            *(float4*)&adjb[(size_t)(bi * TILE + r) * MAX_NODES + bj * TILE + cb * 4] = pv;
            float4 tv;
            tv.x = P[cb * 4 + 0][r];
            tv.y = P[cb * 4 + 1][r];
            tv.z = P[cb * 4 + 2][r];
            tv.w = P[cb * 4 + 3][r];
            *(float4*)&adjb[(size_t)(bj * TILE + r) * MAX_NODES + bi * TILE + cb * 4] = tv;
        }
    } else {
        for (int idx = tid; idx < TILE * TILE; idx += 256) {
            const int r = idx >> 6, c = idx & 63;
            const float v = (r < c) ? P[r][c] : (r > c ? P[c][r] : 0.0f);
            adjb[(size_t)(bi * TILE + r) * MAX_NODES + bi * TILE + c] = v;
        }
    }
}

// ---------------------------------------------------------------------------
extern "C" void kernel_launch(void* const* d_in, const int* in_sizes, int n_in,
                              void* d_out, int out_size, void* d_ws, size_t ws_size,
                              hipStream_t stream)
{
    const float* z   = (const float*)d_in[0];
    const float* W1  = (const float*)d_in[1];
    const float* b1  = (const float*)d_in[2];
    const float* W2  = (const float*)d_in[3];
    const float* b2  = (const float*)d_in[4];
    const float* E1  = (const float*)d_in[5];
    const float* eb1 = (const float*)d_in[6];
    const float* E2  = (const float*)d_in[7];
    const float* eb2 = (const float*)d_in[8];

    float* nodes_out = (float*)d_out;                                   // [32,512,8]
    float* adj       = (float*)d_out + BATCH * MAX_NODES * NODE_DIM;    // [32,512,512]

    dim3 gA(BATCH, 8);
    node_gen<<<gA, 128, 0, stream>>>(z, W1, b1, W2, b2, nodes_out);

    dim3 gB(NUPPER, BATCH);
    edge_gen<<<gB, 256, 0, stream>>>(nodes_out, E1, eb1, E2, eb2, adj);
}

// Round 3
// 60.174 us; speedup vs baseline: 1.0342x; 1.0342x over previous
//
#include <hip/hip_runtime.h>

#define BATCH 32
#define LATENT 128
#define NODE_DIM 8
#define MAX_NODES 512
#define H_NODE 128
#define H_EDGE 64

typedef float f32x2 __attribute__((ext_vector_type(2)));

// ws layout: UPK[32][32][512][2] (4MB) | V[32][512][64] (4MB)
#define UPK_ELEMS (BATCH * 32 * MAX_NODES * 2)

// ---------------------------------------------------------------------------
// Kernel 1: h = relu(z@W1+b1); nodes = h@W2+b2 (written to d_out);
//           U' = eb1 + nodes@E1a  -> UPK[b][c2][i][2]  (pair-interleaved)
//           V' = nodes@E1b        -> V[b][i][64]
// Grid (BATCH, 16): block owns 32 nodes (256 output cols).
// ---------------------------------------------------------------------------
__global__ __launch_bounds__(256) void gen_nodes_uv(
    const float* __restrict__ z,  const float* __restrict__ W1,
    const float* __restrict__ b1, const float* __restrict__ W2,
    const float* __restrict__ b2, const float* __restrict__ E1,
    const float* __restrict__ eb1,
    float* __restrict__ nodes_out, float* __restrict__ UPK,
    float* __restrict__ Vws)
{
    const int b      = blockIdx.x;
    const int mslice = blockIdx.y;     // 0..15, 256 cols each
    const int tid    = threadIdx.x;    // 0..255
    const int i0     = mslice * 32;    // first node owned by this block

    __shared__ float sz[LATENT];
    __shared__ float sh[H_NODE];
    __shared__ float sE1[2 * NODE_DIM][H_EDGE];
    __shared__ float sEb1[H_EDGE];
    __shared__ float sN[32][NODE_DIM];

    if (tid < LATENT) sz[tid] = z[b * LATENT + tid];
    { // stage E1 (1024 floats) + eb1
        for (int idx = tid; idx < 2 * NODE_DIM * H_EDGE; idx += 256)
            (&sE1[0][0])[idx] = E1[idx];
        if (tid < H_EDGE) sEb1[tid] = eb1[tid];
    }
    __syncthreads();

    if (tid < H_NODE) {
        float acc = b1[tid];
#pragma unroll 8
        for (int k = 0; k < LATENT; ++k)
            acc += sz[k] * W1[k * H_NODE + tid];
        sh[tid] = fmaxf(acc, 0.0f);
    }
    __syncthreads();

    // nodes: one output column per thread, coalesced W2 reads
    const int m = mslice * 256 + tid;
    float acc = b2[m];
#pragma unroll 8
    for (int k = 0; k < H_NODE; ++k)
        acc += sh[k] * W2[(size_t)k * (MAX_NODES * NODE_DIM) + m];
    nodes_out[(size_t)b * (MAX_NODES * NODE_DIM) + m] = acc;
    sN[tid >> 3][tid & 7] = acc;
    __syncthreads();

    // U': c2 = rep*8 + (tid>>5), il = tid&31  -> coalesced 8B-stride writes
    {
        const int il = tid & 31;
        const int cg = tid >> 5;       // 0..7
#pragma unroll
        for (int rep = 0; rep < 4; ++rep) {
            const int c2 = rep * 8 + cg;
            const int c  = 2 * c2;
            float ua = sEb1[c], ub = sEb1[c + 1];
#pragma unroll
            for (int d = 0; d < NODE_DIM; ++d) {
                const float nd = sN[il][d];
                ua += nd * sE1[d][c];
                ub += nd * sE1[d][c + 1];
            }
            f32x2 uu = {ua, ub};
            *(f32x2*)&UPK[(((size_t)b * 32 + c2) * MAX_NODES + i0 + il) * 2] = uu;
        }
    }
    // V': jl = tid>>3, cq = tid&7 -> per-row 64B chunks, coalesced
    {
        const int jl = tid >> 3;       // 0..31
        const int cq = tid & 7;        // 0..7
#pragma unroll
        for (int rep = 0; rep < 4; ++rep) {
            const int c2 = rep * 8 + cq;
            const int c  = 2 * c2;
            float va = 0.f, vb = 0.f;
#pragma unroll
            for (int d = 0; d < NODE_DIM; ++d) {
                const float nd = sN[jl][d];
                va += nd * sE1[NODE_DIM + d][c];
                vb += nd * sE1[NODE_DIM + d][c + 1];
            }
            f32x2 vv = {va, vb};
            *(f32x2*)&Vws[((size_t)(b * MAX_NODES + i0 + jl) << 6) + c] = vv;
        }
    }
}

// ---------------------------------------------------------------------------
// Kernel 2: edge probabilities + adjacency.
// 1 wave per block. Tile: 64 i x 16 j, tiles with bjq >= 4*bi (144 of them).
// U rows in VGPRs (64/lane); V rows + E2 via scalar loads (block-uniform);
// packed-f32 inner loop; zero LDS traffic in the hot loop.
// ---------------------------------------------------------------------------
__global__ __launch_bounds__(64, 4) void edge_gen(
    const float* __restrict__ UPK, const float* __restrict__ Vws,
    const float* __restrict__ E2,  const float* __restrict__ eb2,
    float* __restrict__ adj)
{
    const int b = blockIdx.y;
    // decode tile pair: bi in 0..7 (64-wide i), bjq in 4*bi..31 (16-wide j)
    int t = blockIdx.x, bi = 0, cnt;
    while (t >= (cnt = 32 - 4 * bi)) { t -= cnt; ++bi; }
    const int bjq = 4 * bi + t;
    const bool partial = (bjq >> 2) == bi;   // j-range inside i-range

    const int lane = threadIdx.x;            // = i offset
    const int i0 = bi * 64, j0 = bjq * 16;
    const int i  = i0 + lane;

    __shared__ float P[16][65];

    // load this lane's U row (64 ch) as 32 packed pairs — coalesced per c2
    f32x2 u[32];
#pragma unroll
    for (int c2 = 0; c2 < 32; ++c2)
        u[c2] = *(const f32x2*)&UPK[(((size_t)b * 32 + c2) * MAX_NODES + i) * 2];

    const float bias = eb2[0];
    float* adjb = adj + (size_t)b * MAX_NODES * MAX_NODES;
    const f32x2 zero2 = {0.f, 0.f};

#pragma unroll 2
    for (int jj = 0; jj < 16; ++jj) {
        const int j = j0 + jj;
        const float* vrow = Vws + ((size_t)(b * MAX_NODES + j) << 6);

        f32x2 a0 = zero2, a1 = zero2;
#pragma unroll
        for (int c2 = 0; c2 < 32; c2 += 2) {
            const f32x2 v0 = *(const f32x2*)(vrow + 2 * c2);
            const f32x2 v1 = *(const f32x2*)(vrow + 2 * c2 + 2);
            const f32x2 w0 = *(const f32x2*)(E2 + 2 * c2);
            const f32x2 w1 = *(const f32x2*)(E2 + 2 * c2 + 2);
            f32x2 t0 = u[c2] + v0;
            f32x2 t1 = u[c2 + 1] + v1;
            t0 = __builtin_elementwise_max(t0, zero2);
            t1 = __builtin_elementwise_max(t1, zero2);
            a0 += w0 * t0;
            a1 += w1 * t1;
        }
        const float x = a0.x + a0.y + a1.x + a1.y + bias;
        const float p = __builtin_amdgcn_rcpf(1.0f + __expf(-x));

        if (!partial) {
            adjb[(size_t)j * MAX_NODES + i] = p;    // mirror row, coalesced
            P[jj][lane] = p;                        // stage for transpose
        } else {
            const float pv = (i < j) ? p : 0.0f;
            if (i <= j) adjb[(size_t)j * MAX_NODES + i] = pv;  // mirror + diag 0
            if (i <  j) adjb[(size_t)i * MAX_NODES + j] = p;   // upper, scalar
        }
    }

    if (!partial) {
        __syncthreads();   // single wave: cheap; orders LDS writes->reads
#pragma unroll
        for (int cb = 0; cb < 4; ++cb) {
            float4 o;
            o.x = P[4 * cb + 0][lane];
            o.y = P[4 * cb + 1][lane];
            o.z = P[4 * cb + 2][lane];
            o.w = P[4 * cb + 3][lane];
            *(float4*)&adjb[(size_t)i * MAX_NODES + j0 + 4 * cb] = o;
        }
    }
}

// ---------------------------------------------------------------------------
extern "C" void kernel_launch(void* const* d_in, const int* in_sizes, int n_in,
                              void* d_out, int out_size, void* d_ws, size_t ws_size,
                              hipStream_t stream)
{
    const float* z   = (const float*)d_in[0];
    const float* W1  = (const float*)d_in[1];
    const float* b1  = (const float*)d_in[2];
    const float* W2  = (const float*)d_in[3];
    const float* b2  = (const float*)d_in[4];
    const float* E1  = (const float*)d_in[5];
    const float* eb1 = (const float*)d_in[6];
    const float* E2  = (const float*)d_in[7];
    const float* eb2 = (const float*)d_in[8];

    float* nodes_out = (float*)d_out;                                   // [32,512,8]
    float* adj       = (float*)d_out + BATCH * MAX_NODES * NODE_DIM;    // [32,512,512]

    float* UPK = (float*)d_ws;                 // 4 MB
    float* Vws = UPK + UPK_ELEMS;              // 4 MB

    dim3 g1(BATCH, 16);
    gen_nodes_uv<<<g1, 256, 0, stream>>>(z, W1, b1, W2, b2, E1, eb1,
                                         nodes_out, UPK, Vws);

    dim3 g2(144, BATCH);
    edge_gen<<<g2, 64, 0, stream>>>(UPK, Vws, E2, eb2, adj);
}

// Round 4
// 50.465 us; speedup vs baseline: 1.2332x; 1.1924x over previous
//
#include <hip/hip_runtime.h>

#define BATCH 32
#define LATENT 128
#define NODE_DIM 8
#define MAX_NODES 512
#define H_NODE 128
#define H_EDGE 64

typedef float f32x2 __attribute__((ext_vector_type(2)));

// ws layout: UPK[32][32][512][2] (4MB) | V[32][512][64] (4MB)
#define UPK_ELEMS (BATCH * 32 * MAX_NODES * 2)

// ---------------------------------------------------------------------------
// Kernel 1 (UNCHANGED from R3): nodes + U/V precompute.
// ---------------------------------------------------------------------------
__global__ __launch_bounds__(256) void gen_nodes_uv(
    const float* __restrict__ z,  const float* __restrict__ W1,
    const float* __restrict__ b1, const float* __restrict__ W2,
    const float* __restrict__ b2, const float* __restrict__ E1,
    const float* __restrict__ eb1,
    float* __restrict__ nodes_out, float* __restrict__ UPK,
    float* __restrict__ Vws)
{
    const int b      = blockIdx.x;
    const int mslice = blockIdx.y;     // 0..15, 256 cols each
    const int tid    = threadIdx.x;    // 0..255
    const int i0     = mslice * 32;    // first node owned by this block

    __shared__ float sz[LATENT];
    __shared__ float sh[H_NODE];
    __shared__ float sE1[2 * NODE_DIM][H_EDGE];
    __shared__ float sEb1[H_EDGE];
    __shared__ float sN[32][NODE_DIM];

    if (tid < LATENT) sz[tid] = z[b * LATENT + tid];
    for (int idx = tid; idx < 2 * NODE_DIM * H_EDGE; idx += 256)
        (&sE1[0][0])[idx] = E1[idx];
    if (tid < H_EDGE) sEb1[tid] = eb1[tid];
    __syncthreads();

    if (tid < H_NODE) {
        float acc = b1[tid];
#pragma unroll 8
        for (int k = 0; k < LATENT; ++k)
            acc += sz[k] * W1[k * H_NODE + tid];
        sh[tid] = fmaxf(acc, 0.0f);
    }
    __syncthreads();

    const int m = mslice * 256 + tid;
    float acc = b2[m];
#pragma unroll 8
    for (int k = 0; k < H_NODE; ++k)
        acc += sh[k] * W2[(size_t)k * (MAX_NODES * NODE_DIM) + m];
    nodes_out[(size_t)b * (MAX_NODES * NODE_DIM) + m] = acc;
    sN[tid >> 3][tid & 7] = acc;
    __syncthreads();

    {
        const int il = tid & 31;
        const int cg = tid >> 5;
#pragma unroll
        for (int rep = 0; rep < 4; ++rep) {
            const int c2 = rep * 8 + cg;
            const int c  = 2 * c2;
            float ua = sEb1[c], ub = sEb1[c + 1];
#pragma unroll
            for (int d = 0; d < NODE_DIM; ++d) {
                const float nd = sN[il][d];
                ua += nd * sE1[d][c];
                ub += nd * sE1[d][c + 1];
            }
            f32x2 uu = {ua, ub};
            *(f32x2*)&UPK[(((size_t)b * 32 + c2) * MAX_NODES + i0 + il) * 2] = uu;
        }
    }
    {
        const int jl = tid >> 3;
        const int cq = tid & 7;
#pragma unroll
        for (int rep = 0; rep < 4; ++rep) {
            const int c2 = rep * 8 + cq;
            const int c  = 2 * c2;
            float va = 0.f, vb = 0.f;
#pragma unroll
            for (int d = 0; d < NODE_DIM; ++d) {
                const float nd = sN[jl][d];
                va += nd * sE1[NODE_DIM + d][c];
                vb += nd * sE1[NODE_DIM + d][c + 1];
            }
            f32x2 vv = {va, vb};
            *(f32x2*)&Vws[((size_t)(b * MAX_NODES + i0 + jl) << 6) + c] = vv;
        }
    }
}

// ---------------------------------------------------------------------------
// Kernel 2: edge probabilities + adjacency.
// Block = 256 thr (4 waves), tile 64 i x 32 j. Lane owns i; wave w owns 8 j.
// U in VGPRs (coalesced loads); V tile staged in LDS, read via broadcast
// ds_read (conflict-free); E2 uniform -> SGPRs. 72 tiles/batch (jt >= 2*bi).
// ---------------------------------------------------------------------------
__global__ __launch_bounds__(256) void edge_gen(
    const float* __restrict__ UPK, const float* __restrict__ Vws,
    const float* __restrict__ E2,  const float* __restrict__ eb2,
    float* __restrict__ adj)
{
    const int b = blockIdx.y;
    // decode tile: bi in 0..7 (64-wide i), jt in 2*bi..15 (32-wide j)
    int t = blockIdx.x, bi = 0;
    while (t >= 16 - 2 * bi) { t -= 16 - 2 * bi; ++bi; }
    const int jt = 2 * bi + t;
    const bool partial = (jt >> 1) == bi;    // j-range inside i-block

    const int tid  = threadIdx.x;
    const int lane = tid & 63;
    const int wv   = tid >> 6;               // 0..3
    const int i0 = bi * 64, j0 = jt * 32;
    const int i  = i0 + lane;

    __shared__ float sV[32][H_EDGE];         // V rows for the j-tile (8 KB)
    __shared__ float P[32][65];              // tile probs for mirror transpose

    // stage V tile: 8 KB contiguous, 2 float4 per thread
    {
        const float4* src = (const float4*)(Vws + ((size_t)(b * MAX_NODES + j0) << 6));
        float4* dst = (float4*)&sV[0][0];
        dst[tid]       = src[tid];
        dst[tid + 256] = src[tid + 256];
    }

    // this lane's U row: 32 packed pairs, coalesced per c2
    f32x2 u[32];
#pragma unroll
    for (int c2 = 0; c2 < 32; ++c2)
        u[c2] = *(const f32x2*)&UPK[(((size_t)b * 32 + c2) * MAX_NODES + i) * 2];

    const float bias = eb2[0];
    const f32x2 zero2 = {0.f, 0.f};
    float* adjb = adj + (size_t)b * MAX_NODES * MAX_NODES;
    __syncthreads();

#pragma unroll 2
    for (int jj = 0; jj < 8; ++jj) {
        const int jl = wv * 8 + jj;          // 0..31
        const int j  = j0 + jl;
        const float* vrow = &sV[jl][0];      // broadcast LDS reads

        f32x2 a0 = zero2, a1 = zero2;
#pragma unroll
        for (int c2 = 0; c2 < 32; c2 += 2) {
            const f32x2 v0 = *(const f32x2*)(vrow + 2 * c2);
            const f32x2 v1 = *(const f32x2*)(vrow + 2 * c2 + 2);
            const f32x2 w0 = *(const f32x2*)(E2 + 2 * c2);
            const f32x2 w1 = *(const f32x2*)(E2 + 2 * c2 + 2);
            f32x2 t0 = u[c2] + v0;
            f32x2 t1 = u[c2 + 1] + v1;
            t0 = __builtin_elementwise_max(t0, zero2);
            t1 = __builtin_elementwise_max(t1, zero2);
            a0 += w0 * t0;
            a1 += w1 * t1;
        }
        const float x = a0.x + a0.y + a1.x + a1.y + bias;
        const float p = __builtin_amdgcn_rcpf(1.0f + __expf(-x));

        if (!partial) {
            adjb[(size_t)j * MAX_NODES + i] = p;     // lower half, coalesced
            P[jl][lane] = p;                         // stage for mirror
        } else {
            if (i <= j) adjb[(size_t)j * MAX_NODES + i] = (i < j) ? p : 0.0f;
            if (i <  j) adjb[(size_t)i * MAX_NODES + j] = p;
        }
    }

    if (!partial) {
        __syncthreads();
        // mirror: adj[i][j0..j0+31]; thread t -> i = t&63, 8-float chunk q = t>>6
        const int mi = i0 + (tid & 63);
        const int q  = tid >> 6;             // 0..3
        float* dst = &adjb[(size_t)mi * MAX_NODES + j0 + q * 8];
        float4 o0, o1;
        o0.x = P[q * 8 + 0][tid & 63]; o0.y = P[q * 8 + 1][tid & 63];
        o0.z = P[q * 8 + 2][tid & 63]; o0.w = P[q * 8 + 3][tid & 63];
        o1.x = P[q * 8 + 4][tid & 63]; o1.y = P[q * 8 + 5][tid & 63];
        o1.z = P[q * 8 + 6][tid & 63]; o1.w = P[q * 8 + 7][tid & 63];
        *(float4*)dst       = o0;
        *(float4*)(dst + 4) = o1;
    }
}

// ---------------------------------------------------------------------------
extern "C" void kernel_launch(void* const* d_in, const int* in_sizes, int n_in,
                              void* d_out, int out_size, void* d_ws, size_t ws_size,
                              hipStream_t stream)
{
    const float* z   = (const float*)d_in[0];
    const float* W1  = (const float*)d_in[1];
    const float* b1  = (const float*)d_in[2];
    const float* W2  = (const float*)d_in[3];
    const float* b2  = (const float*)d_in[4];
    const float* E1  = (const float*)d_in[5];
    const float* eb1 = (const float*)d_in[6];
    const float* E2  = (const float*)d_in[7];
    const float* eb2 = (const float*)d_in[8];

    float* nodes_out = (float*)d_out;                                   // [32,512,8]
    float* adj       = (float*)d_out + BATCH * MAX_NODES * NODE_DIM;    // [32,512,512]

    float* UPK = (float*)d_ws;                 // 4 MB
    float* Vws = UPK + UPK_ELEMS;              // 4 MB

    dim3 g1(BATCH, 16);
    gen_nodes_uv<<<g1, 256, 0, stream>>>(z, W1, b1, W2, b2, E1, eb1,
                                         nodes_out, UPK, Vws);

    dim3 g2(72, BATCH);
    edge_gen<<<g2, 256, 0, stream>>>(UPK, Vws, E2, eb2, adj);
}